// Round 2
// baseline (667.022 us; speedup 1.0000x reference)
//
#include <hip/hip_runtime.h>
#include <hip/hip_bf16.h>

#define DD 64   // node embedding dim
#define RR 8    // num relations (fixed by problem)

__device__ __forceinline__ float bf2f(unsigned short u) {
    union { unsigned u; float f; } c; c.u = ((unsigned)u) << 16; return c.f;
}
__device__ __forceinline__ unsigned short f2bf(float f) {
    union { float f; unsigned u; } c; c.f = f;
    unsigned u = c.u;
    u += 0x7FFF + ((u >> 16) & 1);      // round-to-nearest-even
    return (unsigned short)(u >> 16);
}

// ---------------------------------------------------------------------------
// cnt[dst*RR + rel] += 1 per edge
// ---------------------------------------------------------------------------
__global__ void k_count(const int* __restrict__ ei, const int* __restrict__ et,
                        int* __restrict__ cnt, int E)
{
    int e = blockIdx.x * 256 + threadIdx.x;
    if (e < E) atomicAdd(&cnt[(size_t)ei[E + e] * RR + et[e]], 1);
}

// ---------------------------------------------------------------------------
// Bucket allocation: start[n] = running offset of node n's edge bucket.
// Block-level scan (256 nodes) + one global atomic per block. Bucket ORDER
// across nodes is irrelevant (each dst only needs its own contiguous range).
// ---------------------------------------------------------------------------
__global__ __launch_bounds__(256) void k_alloc(
    const int* __restrict__ cnt, int* __restrict__ startv,
    int* __restrict__ headv, int* __restrict__ degv,
    int* __restrict__ counter, int N)
{
    __shared__ int sdata[256];
    __shared__ int sbase;
    const int tid = threadIdx.x;
    const int n = blockIdx.x * 256 + tid;

    int deg = 0;
    if (n < N) {
        const int4* c4 = (const int4*)(cnt + (size_t)n * RR);
        int4 a = c4[0], b = c4[1];
        deg = a.x + a.y + a.z + a.w + b.x + b.y + b.z + b.w;
    }
    sdata[tid] = deg;
    __syncthreads();
    int v = deg;
    #pragma unroll
    for (int off = 1; off < 256; off <<= 1) {
        int t = (tid >= off) ? sdata[tid - off] : 0;
        __syncthreads();
        v += t;
        sdata[tid] = v;
        __syncthreads();
    }
    if (tid == 255) sbase = atomicAdd(counter, v);   // v = block total
    __syncthreads();
    if (n < N) {
        int st = sbase + v - deg;   // exclusive scan position
        startv[n] = st;
        headv[n]  = st;
        degv[n]   = deg;
    }
}

// ---------------------------------------------------------------------------
// Scatter edges into per-dst buckets: sorted[pos] = src | (rel << 24)
// ---------------------------------------------------------------------------
__global__ void k_bucket(const int* __restrict__ ei, const int* __restrict__ et,
                         int* __restrict__ headv, unsigned* __restrict__ sorted,
                         int E)
{
    int e = blockIdx.x * 256 + threadIdx.x;
    if (e < E) {
        int dst = ei[E + e];
        int pos = atomicAdd(&headv[dst], 1);
        sorted[pos] = (unsigned)ei[e] | ((unsigned)et[e] << 24);
    }
}

// ---------------------------------------------------------------------------
// One wave per dst in [c0,c1): gather x[src][lane], accumulate per-relation
// in 8 registers (branchless), scale by 1/cnt, write bf16 agg rows.
// No atomics: one wave owns each dst.
// ---------------------------------------------------------------------------
__global__ __launch_bounds__(256) void k_aggregate(
    const float* __restrict__ x, const unsigned* __restrict__ sorted,
    const int* __restrict__ startv, const int* __restrict__ degv,
    const int* __restrict__ cnt, unsigned short* __restrict__ agg,
    int c0, int c1)
{
    const int dst = c0 + blockIdx.x * 4 + (threadIdx.x >> 6);
    if (dst >= c1) return;
    const int lane = threadIdx.x & 63;
    const int s  = startv[dst];
    const int dg = degv[dst];

    float a0=0.f,a1=0.f,a2=0.f,a3=0.f,a4=0.f,a5=0.f,a6=0.f,a7=0.f;

    int e = s;
    const int eend = s + dg;
    for (; e + 1 < eend; e += 2) {
        unsigned p0 = sorted[e], p1 = sorted[e + 1];
        float v0 = x[(size_t)(p0 & 0xFFFFFFu) * DD + lane];
        float v1 = x[(size_t)(p1 & 0xFFFFFFu) * DD + lane];
        int r0 = p0 >> 24, r1 = p1 >> 24;
        a0 += (r0 == 0) ? v0 : 0.f;  a0 += (r1 == 0) ? v1 : 0.f;
        a1 += (r0 == 1) ? v0 : 0.f;  a1 += (r1 == 1) ? v1 : 0.f;
        a2 += (r0 == 2) ? v0 : 0.f;  a2 += (r1 == 2) ? v1 : 0.f;
        a3 += (r0 == 3) ? v0 : 0.f;  a3 += (r1 == 3) ? v1 : 0.f;
        a4 += (r0 == 4) ? v0 : 0.f;  a4 += (r1 == 4) ? v1 : 0.f;
        a5 += (r0 == 5) ? v0 : 0.f;  a5 += (r1 == 5) ? v1 : 0.f;
        a6 += (r0 == 6) ? v0 : 0.f;  a6 += (r1 == 6) ? v1 : 0.f;
        a7 += (r0 == 7) ? v0 : 0.f;  a7 += (r1 == 7) ? v1 : 0.f;
    }
    if (e < eend) {
        unsigned p0 = sorted[e];
        float v0 = x[(size_t)(p0 & 0xFFFFFFu) * DD + lane];
        int r0 = p0 >> 24;
        a0 += (r0 == 0) ? v0 : 0.f;
        a1 += (r0 == 1) ? v0 : 0.f;
        a2 += (r0 == 2) ? v0 : 0.f;
        a3 += (r0 == 3) ? v0 : 0.f;
        a4 += (r0 == 4) ? v0 : 0.f;
        a5 += (r0 == 5) ? v0 : 0.f;
        a6 += (r0 == 6) ? v0 : 0.f;
        a7 += (r0 == 7) ? v0 : 0.f;
    }

    const int* cr = cnt + (size_t)dst * RR;
    unsigned short* ao = agg + ((size_t)(dst - c0)) * RR * DD + lane;
    ao[0*DD] = f2bf(a0 * (1.f / fmaxf((float)cr[0], 1.f)));
    ao[1*DD] = f2bf(a1 * (1.f / fmaxf((float)cr[1], 1.f)));
    ao[2*DD] = f2bf(a2 * (1.f / fmaxf((float)cr[2], 1.f)));
    ao[3*DD] = f2bf(a3 * (1.f / fmaxf((float)cr[3], 1.f)));
    ao[4*DD] = f2bf(a4 * (1.f / fmaxf((float)cr[4], 1.f)));
    ao[5*DD] = f2bf(a5 * (1.f / fmaxf((float)cr[5], 1.f)));
    ao[6*DD] = f2bf(a6 * (1.f / fmaxf((float)cr[6], 1.f)));
    ao[7*DD] = f2bf(a7 * (1.f / fmaxf((float)cr[7], 1.f)));
}

// ---------------------------------------------------------------------------
// out[n][d] = bias[d] + sum_r agg[n][r][:] @ W_rel[r][:,d] + x[n][:] @ W_root[:,d]
// Block = 256 threads, 64 nodes; loop rr in 0..8 (8 = root). Rows staged in
// LDS (wave-uniform broadcast reads), per-lane W column in registers.
// ---------------------------------------------------------------------------
__global__ __launch_bounds__(256) void k_transform_acc(
    const float* __restrict__ x, const unsigned short* __restrict__ agg,
    const float* __restrict__ Wrel, const float* __restrict__ Wroot,
    const float* __restrict__ bias, float* __restrict__ out, int c0, int c1)
{
    const int nb   = c0 + blockIdx.x * 64;
    const int tid  = threadIdx.x;
    const int lane = tid & 63;
    const int wv   = tid >> 6;
    const int nv   = min(64, c1 - nb);

    __shared__ float xs[64 * DD];

    float accv[16];
    const float bl = bias[lane];
    #pragma unroll
    for (int i = 0; i < 16; ++i) accv[i] = bl;

    for (int rr = 0; rr < RR + 1; ++rr) {
        // ---- stage 64 rows into LDS ----
        if (rr < RR) {
            for (int i = tid; i < 64 * DD / 4; i += 256) {
                int row = i >> 4, col4 = i & 15;
                if (row < nv) {
                    const ushort4 q = *(const ushort4*)(
                        agg + (((size_t)(nb - c0 + row)) * RR + rr) * DD + col4 * 4);
                    float4 f = make_float4(bf2f(q.x), bf2f(q.y), bf2f(q.z), bf2f(q.w));
                    *(float4*)(xs + row * DD + col4 * 4) = f;
                }
            }
        } else {
            for (int i = tid; i < 64 * DD / 4; i += 256) {
                int row = i >> 4, col4 = i & 15;
                if (row < nv)
                    *(float4*)(xs + row * DD + col4 * 4) =
                        *(const float4*)(x + ((size_t)(nb + row)) * DD + col4 * 4);
            }
        }
        // ---- per-lane W column ----
        float w[DD];
        const float* W = (rr < RR) ? (Wrel + (size_t)rr * DD * DD) : Wroot;
        #pragma unroll
        for (int k = 0; k < DD; ++k) w[k] = W[k * DD + lane];

        __syncthreads();

        // ---- 16 nodes per wave, 2-way ILP ----
        #pragma unroll
        for (int ii = 0; ii < 16; ii += 2) {
            const float4* xr0 = (const float4*)(xs + (wv * 16 + ii)     * DD);
            const float4* xr1 = (const float4*)(xs + (wv * 16 + ii + 1) * DD);
            float acc0 = 0.f, acc1 = 0.f;
            #pragma unroll
            for (int k4 = 0; k4 < DD / 4; ++k4) {
                float4 a = xr0[k4];
                float4 b = xr1[k4];
                acc0 = fmaf(a.x, w[k4*4+0], acc0); acc1 = fmaf(b.x, w[k4*4+0], acc1);
                acc0 = fmaf(a.y, w[k4*4+1], acc0); acc1 = fmaf(b.y, w[k4*4+1], acc1);
                acc0 = fmaf(a.z, w[k4*4+2], acc0); acc1 = fmaf(b.z, w[k4*4+2], acc1);
                acc0 = fmaf(a.w, w[k4*4+3], acc0); acc1 = fmaf(b.w, w[k4*4+3], acc1);
            }
            accv[ii]     += acc0;
            accv[ii + 1] += acc1;
        }
        __syncthreads();   // protect next iteration's restaging
    }

    #pragma unroll
    for (int ii = 0; ii < 16; ++ii) {
        int ni = wv * 16 + ii;
        if (ni < nv) out[((size_t)(nb + ni)) * DD + lane] = accv[ii];
    }
}

// ---------------------------------------------------------------------------
// echo edge_index / edge_type into d_out tail as float
// ---------------------------------------------------------------------------
__global__ void k_echo(const int* __restrict__ ei, const int* __restrict__ et,
                       float* __restrict__ out_ei, float* __restrict__ out_et,
                       int E)
{
    int i = blockIdx.x * 256 + threadIdx.x;
    if (i < 2 * E) out_ei[i] = (float)ei[i];
    if (i < E)     out_et[i] = (float)et[i];
}

extern "C" void kernel_launch(void* const* d_in, const int* in_sizes, int n_in,
                              void* d_out, int out_size, void* d_ws, size_t ws_size,
                              hipStream_t stream)
{
    const float* x     = (const float*)d_in[0];
    const int*   ei    = (const int*)d_in[1];
    const int*   et    = (const int*)d_in[2];
    const float* Wrel  = (const float*)d_in[3];
    const float* Wroot = (const float*)d_in[4];
    const float* bias  = (const float*)d_in[5];

    const int N = in_sizes[0] / DD;
    const int E = in_sizes[2];

    float* out    = (float*)d_out;
    float* out_ei = out + (size_t)N * DD;
    float* out_et = out_ei + (size_t)2 * E;

    auto align = [](size_t v) { return (v + 255) & ~(size_t)255; };

    // workspace layout
    size_t p = 0;
    int* cnt = (int*)((char*)d_ws + p);          p += align((size_t)N * RR * 4);
    int* counter = (int*)((char*)d_ws + p);
    size_t zero_bytes = p + 256;                 p += 256;
    int* startv = (int*)((char*)d_ws + p);       p += align((size_t)N * 4);
    int* degv   = (int*)((char*)d_ws + p);       p += align((size_t)N * 4);
    int* headv  = (int*)((char*)d_ws + p);       p += align((size_t)N * 4);
    unsigned* sorted = (unsigned*)((char*)d_ws + p); p += align((size_t)E * 4);
    unsigned short* agg = (unsigned short*)((char*)d_ws + p);
    size_t avail = (ws_size > p) ? ws_size - p : 0;

    const size_t per_node = (size_t)RR * DD * sizeof(unsigned short); // 1 KB
    int chunk = (int)((avail / per_node) & ~(size_t)63);
    if (chunk > N) chunk = (N + 63) & ~(size_t)63;
    if (chunk < 64) chunk = 64;   // assume ws is sane

    hipMemsetAsync(d_ws, 0, zero_bytes, stream);                 // cnt + counter

    k_count <<<dim3((E + 255) / 256), 256, 0, stream>>>(ei, et, cnt, E);
    k_alloc <<<dim3((N + 255) / 256), 256, 0, stream>>>(cnt, startv, headv, degv,
                                                        counter, N);
    k_bucket<<<dim3((E + 255) / 256), 256, 0, stream>>>(ei, et, headv, sorted, E);

    for (int c0 = 0; c0 < N; c0 += chunk) {
        int c1 = min(N, c0 + chunk);
        int nc = c1 - c0;
        k_aggregate    <<<dim3((nc + 3) / 4),   256, 0, stream>>>(
            x, sorted, startv, degv, cnt, agg, c0, c1);
        k_transform_acc<<<dim3((nc + 63) / 64), 256, 0, stream>>>(
            x, agg, Wrel, Wroot, bias, out, c0, c1);
    }

    k_echo<<<dim3((2 * E + 255) / 256), 256, 0, stream>>>(ei, et, out_ei, out_et, E);
}

// Round 3
// 369.015 us; speedup vs baseline: 1.8076x; 1.8076x over previous
//
#include <hip/hip_runtime.h>

#define DD 64          // node embedding dim
#define RR 8           // num relations
#define KA 576         // (RR+1)*DD : agg rows 0..7 + x as "relation 8"
#define NT 18          // K steps = KA/32

typedef short bf16x8 __attribute__((ext_vector_type(8)));   // 8 bf16
typedef float f32x4  __attribute__((ext_vector_type(4)));

__device__ __forceinline__ float bf2f(unsigned short u) {
    union { unsigned u; float f; } c; c.u = ((unsigned)u) << 16; return c.f;
}
__device__ __forceinline__ unsigned short f2bf(float f) {
    union { float f; unsigned u; } c; c.f = f;
    unsigned u = c.u;
    u += 0x7FFF + ((u >> 16) & 1);      // round-to-nearest-even
    return (unsigned short)(u >> 16);
}

// ---------------------------------------------------------------------------
// cnt[dst*RR + rel] += 1 per edge
// ---------------------------------------------------------------------------
__global__ void k_count(const int* __restrict__ ei, const int* __restrict__ et,
                        int* __restrict__ cnt, int E)
{
    int e = blockIdx.x * 256 + threadIdx.x;
    if (e < E) atomicAdd(&cnt[(size_t)ei[E + e] * RR + et[e]], 1);
}

// ---------------------------------------------------------------------------
// Bucket allocation: start[n] = running offset of node n's edge bucket.
// ---------------------------------------------------------------------------
__global__ __launch_bounds__(256) void k_alloc(
    const int* __restrict__ cnt, int* __restrict__ startv,
    int* __restrict__ headv, int* __restrict__ degv,
    int* __restrict__ counter, int N)
{
    __shared__ int sdata[256];
    __shared__ int sbase;
    const int tid = threadIdx.x;
    const int n = blockIdx.x * 256 + tid;

    int deg = 0;
    if (n < N) {
        const int4* c4 = (const int4*)(cnt + (size_t)n * RR);
        int4 a = c4[0], b = c4[1];
        deg = a.x + a.y + a.z + a.w + b.x + b.y + b.z + b.w;
    }
    sdata[tid] = deg;
    __syncthreads();
    int v = deg;
    #pragma unroll
    for (int off = 1; off < 256; off <<= 1) {
        int t = (tid >= off) ? sdata[tid - off] : 0;
        __syncthreads();
        v += t;
        sdata[tid] = v;
        __syncthreads();
    }
    if (tid == 255) sbase = atomicAdd(counter, v);
    __syncthreads();
    if (n < N) {
        int st = sbase + v - deg;
        startv[n] = st;
        headv[n]  = st;
        degv[n]   = deg;
    }
}

// ---------------------------------------------------------------------------
// Scatter edges into per-dst buckets: sorted[pos] = src | (rel << 24)
// ---------------------------------------------------------------------------
__global__ void k_bucket(const int* __restrict__ ei, const int* __restrict__ et,
                         int* __restrict__ headv, unsigned* __restrict__ sorted,
                         int E)
{
    int e = blockIdx.x * 256 + threadIdx.x;
    if (e < E) {
        int dst = ei[E + e];
        int pos = atomicAdd(&headv[dst], 1);
        sorted[pos] = (unsigned)ei[e] | ((unsigned)et[e] << 24);
    }
}

// ---------------------------------------------------------------------------
// Pack Wcat = [W_rel(8) ; W_root] into MFMA-B fragment order, bf16 hi + lo.
// idx = (((t*4 + f)*64) + lane)*8 + i  ->  B[k = t*32+(lane>>4)*8+i][d = f*16+(lane&15)]
// ---------------------------------------------------------------------------
__global__ void k_packW(const float* __restrict__ Wrel, const float* __restrict__ Wroot,
                        unsigned short* __restrict__ Bh, unsigned short* __restrict__ Bl)
{
    int idx = blockIdx.x * 256 + threadIdx.x;
    if (idx >= NT * 4 * 64 * 8) return;
    int i    = idx & 7;
    int lane = (idx >> 3) & 63;
    int f    = (idx >> 9) & 3;
    int t    = idx >> 11;
    int k = t * 32 + (lane >> 4) * 8 + i;
    int d = f * 16 + (lane & 15);
    int r = k >> 6, kk = k & 63;
    float w = (r < RR) ? Wrel[((size_t)r * DD + kk) * DD + d]
                       : Wroot[(size_t)kk * DD + d];
    unsigned short h = f2bf(w);
    Bh[idx] = h;
    Bl[idx] = f2bf(w - bf2f(h));
}

// ---------------------------------------------------------------------------
// One wave per dst: gather x[src][lane], per-relation register accumulation,
// scale by 1/cnt, write bf16 A rows [dst][0..7][*]; row 8 = bf16(x[dst][*]).
// ---------------------------------------------------------------------------
__global__ __launch_bounds__(256) void k_aggregate(
    const float* __restrict__ x, const unsigned* __restrict__ sorted,
    const int* __restrict__ startv, const int* __restrict__ degv,
    const int* __restrict__ cnt, unsigned short* __restrict__ agg,
    int c0, int c1)
{
    const int dst = c0 + blockIdx.x * 4 + (threadIdx.x >> 6);
    if (dst >= c1) return;
    const int lane = threadIdx.x & 63;
    const int s  = startv[dst];
    const int dg = degv[dst];

    float a0=0.f,a1=0.f,a2=0.f,a3=0.f,a4=0.f,a5=0.f,a6=0.f,a7=0.f;

    int e = s;
    const int eend = s + dg;
    for (; e + 1 < eend; e += 2) {
        unsigned p0 = sorted[e], p1 = sorted[e + 1];
        float v0 = x[(size_t)(p0 & 0xFFFFFFu) * DD + lane];
        float v1 = x[(size_t)(p1 & 0xFFFFFFu) * DD + lane];
        int r0 = p0 >> 24, r1 = p1 >> 24;
        a0 += (r0 == 0) ? v0 : 0.f;  a0 += (r1 == 0) ? v1 : 0.f;
        a1 += (r0 == 1) ? v0 : 0.f;  a1 += (r1 == 1) ? v1 : 0.f;
        a2 += (r0 == 2) ? v0 : 0.f;  a2 += (r1 == 2) ? v1 : 0.f;
        a3 += (r0 == 3) ? v0 : 0.f;  a3 += (r1 == 3) ? v1 : 0.f;
        a4 += (r0 == 4) ? v0 : 0.f;  a4 += (r1 == 4) ? v1 : 0.f;
        a5 += (r0 == 5) ? v0 : 0.f;  a5 += (r1 == 5) ? v1 : 0.f;
        a6 += (r0 == 6) ? v0 : 0.f;  a6 += (r1 == 6) ? v1 : 0.f;
        a7 += (r0 == 7) ? v0 : 0.f;  a7 += (r1 == 7) ? v1 : 0.f;
    }
    if (e < eend) {
        unsigned p0 = sorted[e];
        float v0 = x[(size_t)(p0 & 0xFFFFFFu) * DD + lane];
        int r0 = p0 >> 24;
        a0 += (r0 == 0) ? v0 : 0.f;
        a1 += (r0 == 1) ? v0 : 0.f;
        a2 += (r0 == 2) ? v0 : 0.f;
        a3 += (r0 == 3) ? v0 : 0.f;
        a4 += (r0 == 4) ? v0 : 0.f;
        a5 += (r0 == 5) ? v0 : 0.f;
        a6 += (r0 == 6) ? v0 : 0.f;
        a7 += (r0 == 7) ? v0 : 0.f;
    }

    const int* cr = cnt + (size_t)dst * RR;
    unsigned short* ao = agg + (size_t)(dst - c0) * KA + lane;
    ao[0*DD] = f2bf(a0 * (1.f / fmaxf((float)cr[0], 1.f)));
    ao[1*DD] = f2bf(a1 * (1.f / fmaxf((float)cr[1], 1.f)));
    ao[2*DD] = f2bf(a2 * (1.f / fmaxf((float)cr[2], 1.f)));
    ao[3*DD] = f2bf(a3 * (1.f / fmaxf((float)cr[3], 1.f)));
    ao[4*DD] = f2bf(a4 * (1.f / fmaxf((float)cr[4], 1.f)));
    ao[5*DD] = f2bf(a5 * (1.f / fmaxf((float)cr[5], 1.f)));
    ao[6*DD] = f2bf(a6 * (1.f / fmaxf((float)cr[6], 1.f)));
    ao[7*DD] = f2bf(a7 * (1.f / fmaxf((float)cr[7], 1.f)));
    ao[8*DD] = f2bf(x[(size_t)dst * DD + lane]);
}

// ---------------------------------------------------------------------------
// out[64-node tile] = A(64x576) @ (Bh + Bl)(576x64) + bias   via MFMA bf16.
// Block = 4 waves; wave w owns output rows [w*16, w*16+16), 4 col-fragments.
// A-fragments load directly from global (contiguous rows); B from packed order.
// ---------------------------------------------------------------------------
__global__ __launch_bounds__(256) void k_transform_mfma(
    const unsigned short* __restrict__ A,
    const unsigned short* __restrict__ Bh,
    const unsigned short* __restrict__ Bl,
    const float* __restrict__ bias,
    float* __restrict__ out, int c0, int c1)
{
    const int nb   = c0 + blockIdx.x * 64;
    const int wv   = threadIdx.x >> 6;
    const int lane = threadIdx.x & 63;
    const int rlo  = lane & 15;        // A row within 16 / D col within 16
    const int kg   = lane >> 4;        // k-group

    const unsigned short* ap = A + ((size_t)(nb - c0) + wv * 16 + rlo) * KA + kg * 8;

    f32x4 acc0 = {0.f,0.f,0.f,0.f};
    f32x4 acc1 = {0.f,0.f,0.f,0.f};
    f32x4 acc2 = {0.f,0.f,0.f,0.f};
    f32x4 acc3 = {0.f,0.f,0.f,0.f};

    #pragma unroll
    for (int t = 0; t < NT; ++t) {
        bf16x8 a = *(const bf16x8*)(ap + t * 32);
        const unsigned short* bh = Bh + (size_t)t * 2048 + lane * 8;
        const unsigned short* bl = Bl + (size_t)t * 2048 + lane * 8;
        bf16x8 b;
        b = *(const bf16x8*)(bh +    0); acc0 = __builtin_amdgcn_mfma_f32_16x16x32_bf16(a, b, acc0, 0, 0, 0);
        b = *(const bf16x8*)(bh +  512); acc1 = __builtin_amdgcn_mfma_f32_16x16x32_bf16(a, b, acc1, 0, 0, 0);
        b = *(const bf16x8*)(bh + 1024); acc2 = __builtin_amdgcn_mfma_f32_16x16x32_bf16(a, b, acc2, 0, 0, 0);
        b = *(const bf16x8*)(bh + 1536); acc3 = __builtin_amdgcn_mfma_f32_16x16x32_bf16(a, b, acc3, 0, 0, 0);
        b = *(const bf16x8*)(bl +    0); acc0 = __builtin_amdgcn_mfma_f32_16x16x32_bf16(a, b, acc0, 0, 0, 0);
        b = *(const bf16x8*)(bl +  512); acc1 = __builtin_amdgcn_mfma_f32_16x16x32_bf16(a, b, acc1, 0, 0, 0);
        b = *(const bf16x8*)(bl + 1024); acc2 = __builtin_amdgcn_mfma_f32_16x16x32_bf16(a, b, acc2, 0, 0, 0);
        b = *(const bf16x8*)(bl + 1536); acc3 = __builtin_amdgcn_mfma_f32_16x16x32_bf16(a, b, acc3, 0, 0, 0);
    }

    // C/D layout: col = lane&15, row = (lane>>4)*4 + reg
    const float b0 = bias[rlo];
    const float b1 = bias[rlo + 16];
    const float b2 = bias[rlo + 32];
    const float b3 = bias[rlo + 48];
    const int orow = nb + wv * 16 + kg * 4;
    #pragma unroll
    for (int j = 0; j < 4; ++j) {
        int r = orow + j;
        if (r < c1) {
            float* op = out + (size_t)r * DD + rlo;
            op[0]  = acc0[j] + b0;
            op[16] = acc1[j] + b1;
            op[32] = acc2[j] + b2;
            op[48] = acc3[j] + b3;
        }
    }
}

// ---------------------------------------------------------------------------
// echo edge_index / edge_type into d_out tail as float
// ---------------------------------------------------------------------------
__global__ void k_echo(const int* __restrict__ ei, const int* __restrict__ et,
                       float* __restrict__ out_ei, float* __restrict__ out_et,
                       int E)
{
    int i = blockIdx.x * 256 + threadIdx.x;
    if (i < 2 * E) out_ei[i] = (float)ei[i];
    if (i < E)     out_et[i] = (float)et[i];
}

extern "C" void kernel_launch(void* const* d_in, const int* in_sizes, int n_in,
                              void* d_out, int out_size, void* d_ws, size_t ws_size,
                              hipStream_t stream)
{
    const float* x     = (const float*)d_in[0];
    const int*   ei    = (const int*)d_in[1];
    const int*   et    = (const int*)d_in[2];
    const float* Wrel  = (const float*)d_in[3];
    const float* Wroot = (const float*)d_in[4];
    const float* bias  = (const float*)d_in[5];

    const int N = in_sizes[0] / DD;
    const int E = in_sizes[2];

    float* out    = (float*)d_out;
    float* out_ei = out + (size_t)N * DD;
    float* out_et = out_ei + (size_t)2 * E;

    auto align = [](size_t v) { return (v + 255) & ~(size_t)255; };

    // workspace layout
    size_t p = 0;
    int* cnt = (int*)((char*)d_ws + p);              p += align((size_t)N * RR * 4);
    int* counter = (int*)((char*)d_ws + p);
    size_t zero_bytes = p + 256;                     p += 256;
    int* startv = (int*)((char*)d_ws + p);           p += align((size_t)N * 4);
    int* degv   = (int*)((char*)d_ws + p);           p += align((size_t)N * 4);
    int* headv  = (int*)((char*)d_ws + p);           p += align((size_t)N * 4);
    unsigned* sorted = (unsigned*)((char*)d_ws + p); p += align((size_t)E * 4);
    unsigned short* Bh = (unsigned short*)((char*)d_ws + p); p += align((size_t)NT*4*64*8*2);
    unsigned short* Bl = (unsigned short*)((char*)d_ws + p); p += align((size_t)NT*4*64*8*2);
    unsigned short* agg = (unsigned short*)((char*)d_ws + p);
    size_t avail = (ws_size > p) ? ws_size - p : 0;

    const size_t per_node = (size_t)KA * 2;          // 1152 B
    // keep 64 spare rows so padded MFMA A-reads stay in-bounds
    int chunk = (int)(((avail / per_node) - 64) & ~(size_t)63);
    if (chunk > N) chunk = (N + 63) & ~(size_t)63;
    if (chunk < 64) chunk = 64;   // ws is known-large (>=208MB observed)

    hipMemsetAsync(d_ws, 0, zero_bytes, stream);     // cnt + counter

    k_packW <<<dim3((NT*4*64*8 + 255) / 256), 256, 0, stream>>>(Wrel, Wroot, Bh, Bl);
    k_count <<<dim3((E + 255) / 256), 256, 0, stream>>>(ei, et, cnt, E);
    k_alloc <<<dim3((N + 255) / 256), 256, 0, stream>>>(cnt, startv, headv, degv,
                                                        counter, N);
    k_bucket<<<dim3((E + 255) / 256), 256, 0, stream>>>(ei, et, headv, sorted, E);

    for (int c0 = 0; c0 < N; c0 += chunk) {
        int c1 = min(N, c0 + chunk);
        int nc = c1 - c0;
        k_aggregate     <<<dim3((nc + 3) / 4),   256, 0, stream>>>(
            x, sorted, startv, degv, cnt, agg, c0, c1);
        k_transform_mfma<<<dim3((nc + 63) / 64), 256, 0, stream>>>(
            agg, Bh, Bl, bias, out, c0, c1);
    }

    k_echo<<<dim3((2 * E + 255) / 256), 256, 0, stream>>>(ei, et, out_ei, out_et, E);
}

// Round 4
// 315.004 us; speedup vs baseline: 2.1175x; 1.1715x over previous
//
#include <hip/hip_runtime.h>

#define DD 64          // node embedding dim
#define RR 8           // num relations
#define KA 576         // (RR+1)*DD : agg rows 0..7 + x as "relation 8"
#define NT 18          // K steps = KA/32
#define NPART 8        // dst partitions ~ XCDs (blockIdx%8 round-robin)
#define ECH 2048       // edges per slice-block in partitioned kernels

typedef short bf16x8 __attribute__((ext_vector_type(8)));   // 8 bf16
typedef float f32x4  __attribute__((ext_vector_type(4)));

__device__ __forceinline__ float bf2f(unsigned short u) {
    union { unsigned u; float f; } c; c.u = ((unsigned)u) << 16; return c.f;
}
__device__ __forceinline__ unsigned short f2bf(float f) {
    union { float f; unsigned u; } c; c.f = f;
    unsigned u = c.u;
    u += 0x7FFF + ((u >> 16) & 1);      // round-to-nearest-even
    return (unsigned short)(u >> 16);
}

// ---------------------------------------------------------------------------
// Partitioned count: partition p (= blockIdx%8 -> XCD p) handles dst range
// [N*p/8, N*(p+1)/8); each slice-block scans a contiguous edge chunk and
// filters. cnt lines for range p are written only from XCD p -> L2-local
// atomics, single writeback.
// ---------------------------------------------------------------------------
__global__ __launch_bounds__(256) void k_count_part(
    const int* __restrict__ ei, const int* __restrict__ et,
    int* __restrict__ cnt, int E, int N)
{
    const int p   = blockIdx.x & (NPART - 1);
    const int sb  = blockIdx.x / NPART;
    const int dlo = (int)((long long)N * p / NPART);
    const int dhi = (int)((long long)N * (p + 1) / NPART);
    const int e0  = sb * ECH;
    const int e1  = min(E, e0 + ECH);
    for (int e = e0 + threadIdx.x; e < e1; e += 256) {
        int dst = ei[E + e];
        if (dst >= dlo && dst < dhi)
            atomicAdd(&cnt[(size_t)dst * RR + et[e]], 1);
    }
}

// ---------------------------------------------------------------------------
// Bucket allocation: start[n] = running offset of node n's edge bucket.
// ---------------------------------------------------------------------------
__global__ __launch_bounds__(256) void k_alloc(
    const int* __restrict__ cnt, int* __restrict__ startv,
    int* __restrict__ headv, int* __restrict__ degv,
    int* __restrict__ counter, int N)
{
    __shared__ int sdata[256];
    __shared__ int sbase;
    const int tid = threadIdx.x;
    const int n = blockIdx.x * 256 + tid;

    int deg = 0;
    if (n < N) {
        const int4* c4 = (const int4*)(cnt + (size_t)n * RR);
        int4 a = c4[0], b = c4[1];
        deg = a.x + a.y + a.z + a.w + b.x + b.y + b.z + b.w;
    }
    sdata[tid] = deg;
    __syncthreads();
    int v = deg;
    #pragma unroll
    for (int off = 1; off < 256; off <<= 1) {
        int t = (tid >= off) ? sdata[tid - off] : 0;
        __syncthreads();
        v += t;
        sdata[tid] = v;
        __syncthreads();
    }
    if (tid == 255) sbase = atomicAdd(counter, v);
    __syncthreads();
    if (n < N) {
        int st = sbase + v - deg;
        startv[n] = st;
        headv[n]  = st;
        degv[n]   = deg;
    }
}

// ---------------------------------------------------------------------------
// Partitioned bucket scatter: sorted[pos] = src | (rel << 24).
// Same partition->XCD trick: bucket lines for dst range p written only by
// XCD p -> writes coalesce in that L2, writeback ~once per line.
// ---------------------------------------------------------------------------
__global__ __launch_bounds__(256) void k_bucket_part(
    const int* __restrict__ ei, const int* __restrict__ et,
    int* __restrict__ headv, unsigned* __restrict__ sorted, int E, int N)
{
    const int p   = blockIdx.x & (NPART - 1);
    const int sb  = blockIdx.x / NPART;
    const int dlo = (int)((long long)N * p / NPART);
    const int dhi = (int)((long long)N * (p + 1) / NPART);
    const int e0  = sb * ECH;
    const int e1  = min(E, e0 + ECH);
    for (int e = e0 + threadIdx.x; e < e1; e += 256) {
        int dst = ei[E + e];
        if (dst >= dlo && dst < dhi) {
            int pos = atomicAdd(&headv[dst], 1);
            sorted[pos] = (unsigned)ei[e] | ((unsigned)et[e] << 24);
        }
    }
}

// ---------------------------------------------------------------------------
// Pack Wcat = [W_rel(8) ; W_root] into MFMA-B fragment order, bf16 hi + lo.
// ---------------------------------------------------------------------------
__global__ void k_packW(const float* __restrict__ Wrel, const float* __restrict__ Wroot,
                        unsigned short* __restrict__ Bh, unsigned short* __restrict__ Bl)
{
    int idx = blockIdx.x * 256 + threadIdx.x;
    if (idx >= NT * 4 * 64 * 8) return;
    int i    = idx & 7;
    int lane = (idx >> 3) & 63;
    int f    = (idx >> 9) & 3;
    int t    = idx >> 11;
    int k = t * 32 + (lane >> 4) * 8 + i;
    int d = f * 16 + (lane & 15);
    int r = k >> 6, kk = k & 63;
    float w = (r < RR) ? Wrel[((size_t)r * DD + kk) * DD + d]
                       : Wroot[(size_t)kk * DD + d];
    unsigned short h = f2bf(w);
    Bh[idx] = h;
    Bl[idx] = f2bf(w - bf2f(h));
}

// ---------------------------------------------------------------------------
// One wave per dst: gather x[src][lane], per-relation register accumulation
// (4-deep ILP to hide L3 gather latency), scale by 1/cnt, write bf16 A rows.
// ---------------------------------------------------------------------------
__global__ __launch_bounds__(256) void k_aggregate(
    const float* __restrict__ x, const unsigned* __restrict__ sorted,
    const int* __restrict__ startv, const int* __restrict__ degv,
    const int* __restrict__ cnt, unsigned short* __restrict__ agg,
    int c0, int c1)
{
    const int dst = c0 + blockIdx.x * 4 + (threadIdx.x >> 6);
    if (dst >= c1) return;
    const int lane = threadIdx.x & 63;
    const int s  = startv[dst];
    const int dg = degv[dst];

    float a0=0.f,a1=0.f,a2=0.f,a3=0.f,a4=0.f,a5=0.f,a6=0.f,a7=0.f;

    int e = s;
    const int eend = s + dg;
    for (; e + 3 < eend; e += 4) {
        unsigned p0 = sorted[e],     p1 = sorted[e + 1];
        unsigned p2 = sorted[e + 2], p3 = sorted[e + 3];
        float v0 = x[(size_t)(p0 & 0xFFFFFFu) * DD + lane];
        float v1 = x[(size_t)(p1 & 0xFFFFFFu) * DD + lane];
        float v2 = x[(size_t)(p2 & 0xFFFFFFu) * DD + lane];
        float v3 = x[(size_t)(p3 & 0xFFFFFFu) * DD + lane];
        int r0 = p0 >> 24, r1 = p1 >> 24, r2 = p2 >> 24, r3 = p3 >> 24;
        a0 += (r0==0)?v0:0.f; a0 += (r1==0)?v1:0.f; a0 += (r2==0)?v2:0.f; a0 += (r3==0)?v3:0.f;
        a1 += (r0==1)?v0:0.f; a1 += (r1==1)?v1:0.f; a1 += (r2==1)?v2:0.f; a1 += (r3==1)?v3:0.f;
        a2 += (r0==2)?v0:0.f; a2 += (r1==2)?v1:0.f; a2 += (r2==2)?v2:0.f; a2 += (r3==2)?v3:0.f;
        a3 += (r0==3)?v0:0.f; a3 += (r1==3)?v1:0.f; a3 += (r2==3)?v2:0.f; a3 += (r3==3)?v3:0.f;
        a4 += (r0==4)?v0:0.f; a4 += (r1==4)?v1:0.f; a4 += (r2==4)?v2:0.f; a4 += (r3==4)?v3:0.f;
        a5 += (r0==5)?v0:0.f; a5 += (r1==5)?v1:0.f; a5 += (r2==5)?v2:0.f; a5 += (r3==5)?v3:0.f;
        a6 += (r0==6)?v0:0.f; a6 += (r1==6)?v1:0.f; a6 += (r2==6)?v2:0.f; a6 += (r3==6)?v3:0.f;
        a7 += (r0==7)?v0:0.f; a7 += (r1==7)?v1:0.f; a7 += (r2==7)?v2:0.f; a7 += (r3==7)?v3:0.f;
    }
    for (; e < eend; ++e) {
        unsigned p0 = sorted[e];
        float v0 = x[(size_t)(p0 & 0xFFFFFFu) * DD + lane];
        int r0 = p0 >> 24;
        a0 += (r0==0)?v0:0.f; a1 += (r0==1)?v0:0.f;
        a2 += (r0==2)?v0:0.f; a3 += (r0==3)?v0:0.f;
        a4 += (r0==4)?v0:0.f; a5 += (r0==5)?v0:0.f;
        a6 += (r0==6)?v0:0.f; a7 += (r0==7)?v0:0.f;
    }

    const int* cr = cnt + (size_t)dst * RR;
    unsigned short* ao = agg + (size_t)(dst - c0) * KA + lane;
    ao[0*DD] = f2bf(a0 * (1.f / fmaxf((float)cr[0], 1.f)));
    ao[1*DD] = f2bf(a1 * (1.f / fmaxf((float)cr[1], 1.f)));
    ao[2*DD] = f2bf(a2 * (1.f / fmaxf((float)cr[2], 1.f)));
    ao[3*DD] = f2bf(a3 * (1.f / fmaxf((float)cr[3], 1.f)));
    ao[4*DD] = f2bf(a4 * (1.f / fmaxf((float)cr[4], 1.f)));
    ao[5*DD] = f2bf(a5 * (1.f / fmaxf((float)cr[5], 1.f)));
    ao[6*DD] = f2bf(a6 * (1.f / fmaxf((float)cr[6], 1.f)));
    ao[7*DD] = f2bf(a7 * (1.f / fmaxf((float)cr[7], 1.f)));
    ao[8*DD] = f2bf(x[(size_t)dst * DD + lane]);
}

// ---------------------------------------------------------------------------
// out[64-node tile] = A(64x576) @ (Bh + Bl)(576x64) + bias   via MFMA bf16.
// ---------------------------------------------------------------------------
__global__ __launch_bounds__(256) void k_transform_mfma(
    const unsigned short* __restrict__ A,
    const unsigned short* __restrict__ Bh,
    const unsigned short* __restrict__ Bl,
    const float* __restrict__ bias,
    float* __restrict__ out, int c0, int c1)
{
    const int nb   = c0 + blockIdx.x * 64;
    const int wv   = threadIdx.x >> 6;
    const int lane = threadIdx.x & 63;
    const int rlo  = lane & 15;        // A row within 16 / D col within 16
    const int kg   = lane >> 4;        // k-group

    const unsigned short* ap = A + ((size_t)(nb - c0) + wv * 16 + rlo) * KA + kg * 8;

    f32x4 acc0 = {0.f,0.f,0.f,0.f};
    f32x4 acc1 = {0.f,0.f,0.f,0.f};
    f32x4 acc2 = {0.f,0.f,0.f,0.f};
    f32x4 acc3 = {0.f,0.f,0.f,0.f};

    #pragma unroll
    for (int t = 0; t < NT; ++t) {
        bf16x8 a = *(const bf16x8*)(ap + t * 32);
        const unsigned short* bh = Bh + (size_t)t * 2048 + lane * 8;
        const unsigned short* bl = Bl + (size_t)t * 2048 + lane * 8;
        bf16x8 b;
        b = *(const bf16x8*)(bh +    0); acc0 = __builtin_amdgcn_mfma_f32_16x16x32_bf16(a, b, acc0, 0, 0, 0);
        b = *(const bf16x8*)(bh +  512); acc1 = __builtin_amdgcn_mfma_f32_16x16x32_bf16(a, b, acc1, 0, 0, 0);
        b = *(const bf16x8*)(bh + 1024); acc2 = __builtin_amdgcn_mfma_f32_16x16x32_bf16(a, b, acc2, 0, 0, 0);
        b = *(const bf16x8*)(bh + 1536); acc3 = __builtin_amdgcn_mfma_f32_16x16x32_bf16(a, b, acc3, 0, 0, 0);
        b = *(const bf16x8*)(bl +    0); acc0 = __builtin_amdgcn_mfma_f32_16x16x32_bf16(a, b, acc0, 0, 0, 0);
        b = *(const bf16x8*)(bl +  512); acc1 = __builtin_amdgcn_mfma_f32_16x16x32_bf16(a, b, acc1, 0, 0, 0);
        b = *(const bf16x8*)(bl + 1024); acc2 = __builtin_amdgcn_mfma_f32_16x16x32_bf16(a, b, acc2, 0, 0, 0);
        b = *(const bf16x8*)(bl + 1536); acc3 = __builtin_amdgcn_mfma_f32_16x16x32_bf16(a, b, acc3, 0, 0, 0);
    }

    // C/D layout: col = lane&15, row = (lane>>4)*4 + reg
    const float b0 = bias[rlo];
    const float b1 = bias[rlo + 16];
    const float b2 = bias[rlo + 32];
    const float b3 = bias[rlo + 48];
    const int orow = nb + wv * 16 + kg * 4;
    #pragma unroll
    for (int j = 0; j < 4; ++j) {
        int r = orow + j;
        if (r < c1) {
            float* op = out + (size_t)r * DD + rlo;
            op[0]  = acc0[j] + b0;
            op[16] = acc1[j] + b1;
            op[32] = acc2[j] + b2;
            op[48] = acc3[j] + b3;
        }
    }
}

// ---------------------------------------------------------------------------
// echo edge_index / edge_type into d_out tail as float
// ---------------------------------------------------------------------------
__global__ void k_echo(const int* __restrict__ ei, const int* __restrict__ et,
                       float* __restrict__ out_ei, float* __restrict__ out_et,
                       int E)
{
    int i = blockIdx.x * 256 + threadIdx.x;
    if (i < 2 * E) out_ei[i] = (float)ei[i];
    if (i < E)     out_et[i] = (float)et[i];
}

extern "C" void kernel_launch(void* const* d_in, const int* in_sizes, int n_in,
                              void* d_out, int out_size, void* d_ws, size_t ws_size,
                              hipStream_t stream)
{
    const float* x     = (const float*)d_in[0];
    const int*   ei    = (const int*)d_in[1];
    const int*   et    = (const int*)d_in[2];
    const float* Wrel  = (const float*)d_in[3];
    const float* Wroot = (const float*)d_in[4];
    const float* bias  = (const float*)d_in[5];

    const int N = in_sizes[0] / DD;
    const int E = in_sizes[2];

    float* out    = (float*)d_out;
    float* out_ei = out + (size_t)N * DD;
    float* out_et = out_ei + (size_t)2 * E;

    auto align = [](size_t v) { return (v + 255) & ~(size_t)255; };

    // workspace layout
    size_t p = 0;
    int* cnt = (int*)((char*)d_ws + p);              p += align((size_t)N * RR * 4);
    int* counter = (int*)((char*)d_ws + p);
    size_t zero_bytes = p + 256;                     p += 256;
    int* startv = (int*)((char*)d_ws + p);           p += align((size_t)N * 4);
    int* degv   = (int*)((char*)d_ws + p);           p += align((size_t)N * 4);
    int* headv  = (int*)((char*)d_ws + p);           p += align((size_t)N * 4);
    unsigned* sorted = (unsigned*)((char*)d_ws + p); p += align((size_t)E * 4);
    unsigned short* Bh = (unsigned short*)((char*)d_ws + p); p += align((size_t)NT*4*64*8*2);
    unsigned short* Bl = (unsigned short*)((char*)d_ws + p); p += align((size_t)NT*4*64*8*2);
    unsigned short* agg = (unsigned short*)((char*)d_ws + p);
    size_t avail = (ws_size > p) ? ws_size - p : 0;

    const size_t per_node = (size_t)KA * 2;          // 1152 B
    int chunk = (int)(((avail / per_node) - 64) & ~(size_t)63);
    if (chunk > N) chunk = (N + 63) & ~(size_t)63;
    if (chunk < 64) chunk = 64;

    hipMemsetAsync(d_ws, 0, zero_bytes, stream);     // cnt + counter

    const int nsb = (E + ECH - 1) / ECH;             // slice-blocks per partition

    k_packW <<<dim3((NT*4*64*8 + 255) / 256), 256, 0, stream>>>(Wrel, Wroot, Bh, Bl);
    k_count_part <<<dim3(nsb * NPART), 256, 0, stream>>>(ei, et, cnt, E, N);
    k_alloc <<<dim3((N + 255) / 256), 256, 0, stream>>>(cnt, startv, headv, degv,
                                                        counter, N);
    k_bucket_part<<<dim3(nsb * NPART), 256, 0, stream>>>(ei, et, headv, sorted, E, N);

    for (int c0 = 0; c0 < N; c0 += chunk) {
        int c1 = min(N, c0 + chunk);
        int nc = c1 - c0;
        k_aggregate     <<<dim3((nc + 3) / 4),   256, 0, stream>>>(
            x, sorted, startv, degv, cnt, agg, c0, c1);
        k_transform_mfma<<<dim3((nc + 63) / 64), 256, 0, stream>>>(
            agg, Bh, Bl, bias, out, c0, c1);
    }

    k_echo<<<dim3((2 * E + 255) / 256), 256, 0, stream>>>(ei, et, out_ei, out_et, E);
}